// Round 9
// baseline (211.100 us; speedup 1.0000x reference)
//
#include <hip/hip_runtime.h>

// E = sum over 4 directional diffs squared of avgpool4(mean_c(org - enhance)).
// R9: test the LAST untried read path — global_load_lds DMA (HBM->LDS direct,
// no VGPR return / L1 allocation). Evidence: reads plateau at ~3.56 TB/s
// across every access structure (R0..R8) while write-only fills run 6.7 TB/s
// -> per-CU read-return-path cap suspected. One block per (b,py) strip;
// 4 waves stage 48 chunks x 1 KiB (org+enh, 3ch x 4 rows x 512 floats) into
// LDS, barrier, pool 4x4 out of LDS, LDS pair-exchange, write p (2 MB).
// Kernel 2: unchanged 5-point stencil on p.

__device__ __forceinline__ void gload_lds16(const float* g, float* l) {
  __builtin_amdgcn_global_load_lds(
      (const __attribute__((address_space(1))) void*)g,
      (__attribute__((address_space(3))) void*)l, 16, 0, 0);
}

typedef float f4 __attribute__((ext_vector_type(4)));

__global__ __launch_bounds__(256) void pool_diff_kernel(
    const float* __restrict__ org, const float* __restrict__ enh,
    float* __restrict__ p) {
  __shared__ float lds[12288];    // 48 KB: org strips [0,6144), enh [6144,12288)
  __shared__ float red[128];
  int t = threadIdx.x;
  int lane = t & 63;
  int w = t >> 6;                 // wave id 0..3
  int s = blockIdx.x;             // strip id = b*128 + py
  int b = s >> 7;
  int py = s & 127;
  int sbase = b * 786432 + py * 2048;   // float units; channel stride 262144

  // Stage 48 chunks of 1 KiB; wave w owns chunks w*12 .. w*12+11.
  // Chunk gc: gc<24 -> org local chunk gc; else enh chunk gc-24.
  // Local chunk lc: ch = lc>>3, k = lc&7 -> floats ch*262144 + k*256 (+lane*4).
#pragma unroll
  for (int c = 0; c < 12; ++c) {
    int gc = w * 12 + c;                  // wave-uniform
    const float* src = (gc < 24) ? org : enh;
    int lc = (gc < 24) ? gc : gc - 24;
    int ch = lc >> 3;
    int k  = lc & 7;
    const float* gp = src + sbase + ch * 262144 + k * 256 + lane * 4;
    gload_lds16(gp, &lds[gc * 256]);      // lds dest wave-uniform base
  }
  __syncthreads();

  // Pool: thread t owns (px = t&127, rows h and h+2 of each channel), h = t>>7.
  int px = t & 127;
  int h  = t >> 7;
  f4 acc = {0.f, 0.f, 0.f, 0.f};
#pragma unroll
  for (int ch = 0; ch < 3; ++ch) {
    int o = ch * 2048 + px * 4;
    f4 oA = *(const f4*)&lds[o + h * 512];
    f4 oB = *(const f4*)&lds[o + (h + 2) * 512];
    f4 eA = *(const f4*)&lds[6144 + o + h * 512];
    f4 eB = *(const f4*)&lds[6144 + o + (h + 2) * 512];
    acc += (oA - eA) + (oB - eB);
  }
  float mine = acc.x + acc.y + acc.z + acc.w;
  if (h == 1) red[px] = mine;
  __syncthreads();
  if (h == 0) {
    p[b * 16384 + py * 128 + px] = (mine + red[px]) * (1.0f / 48.0f);
  }
}

__global__ __launch_bounds__(256) void espa_stencil_kernel(
    const float* __restrict__ p, float* __restrict__ out) {
  int idx = blockIdx.x * 256 + threadIdx.x;   // = b*16384 + y*128 + x
  int x = idx & 127;
  int y = (idx >> 7) & 127;
  float c = p[idx];
  float l = (x > 0)   ? p[idx - 1]   : 0.f;
  float r = (x < 127) ? p[idx + 1]   : 0.f;
  float u = (y > 0)   ? p[idx - 128] : 0.f;
  float d = (y < 127) ? p[idx + 128] : 0.f;
  float dl = c - l, dr = c - r, du = c - u, dd = c - d;
  out[idx] = dl * dl + dr * dr + du * du + dd * dd;
}

extern "C" void kernel_launch(void* const* d_in, const int* in_sizes, int n_in,
                              void* d_out, int out_size, void* d_ws, size_t ws_size,
                              hipStream_t stream) {
  const float* org = (const float*)d_in[0];
  const float* enh = (const float*)d_in[1];
  float* p   = (float*)d_ws;       // 32*128*128 floats = 2 MB scratch
  float* out = (float*)d_out;      // 32*1*128*128 floats

  pool_diff_kernel<<<4096, 256, 0, stream>>>(org, enh, p);  // one block per (b,py)
  const int N = 32 * 128 * 128;
  espa_stencil_kernel<<<N / 256, 256, 0, stream>>>(p, out);
}